// Round 14
// baseline (307.058 us; speedup 1.0000x reference)
//
#include <hip/hip_runtime.h>
#include <hip/hip_cooperative_groups.h>
#include <stdint.h>

namespace cg = cooperative_groups;

#define BLOCK 256
#define GRIDN 256        // cooperative grid: 1 block/CU
#define KMAX 8
#define NWAVES (BLOCK / 64)
#define S2 2048          // padded N (pow2); N=2000 fits (11-bit indices)
#define NW 32            // 64-bit words per selection mask
#define NCH 32           // 64-element chunks
#define SPB 16           // selector slots per pairs virtual-block
#define PB (S2 / SPB)    // pairs virtual-blocks per image (128)
#define RB (S2 / BLOCK)  // rank tiles per axis (8)
#define NTRI (NCH*(NCH+1)/2)   // 528 lower-tri tiles
#define PCAP 65536
#define LDSP2 4096
#define BCAP 64
#define EFF_INF 0x7FFFFFFF

struct SmallD {
    int bcnt[NCH];
    unsigned long long skilled[NW];
    unsigned long long ssel[NW];
    unsigned long long svalid[NW];
    int pfx[NW + 1];
    float pw[NWAVES][4];
    unsigned wsum[NWAVES];
    int bm[NWAVES];
    int sV;
    int anyact;
};

// =====================================================================
// Mega-kernel: all phases in one cooperative launch, grid.sync() between.
// Phases: P0 rankcount -> P1 scatter -> P2 suppairs -> P3 greedy+eff ->
// P4 pair sums -> P5 finalize.
// =====================================================================
__global__ __launch_bounds__(BLOCK) void mega_kernel(
    const float* __restrict__ pred, const int* __restrict__ gt_inds,
    const float* __restrict__ proposals,
    float* __restrict__ soa, int* __restrict__ sgt, int* __restrict__ rnk,
    unsigned* __restrict__ prs, int* __restrict__ pcn,
    unsigned long long* __restrict__ selw, int* __restrict__ eff,
    int* __restrict__ nst, float* __restrict__ par, float* __restrict__ out,
    int N, int imgs)
{
    cg::grid_group grid = cg::this_grid();
    const int blk = blockIdx.x, t = threadIdx.x;
    const int lane = t & 63, wave = t >> 6;
    const size_t stride = (size_t)imgs * S2;

    __shared__ __align__(16) char SM[43008];
    char* A = SM;                       // 16 KB scratch (phase-dependent)
    unsigned* spair = (unsigned*)(SM + 16384);   // 16 KB
    unsigned* bucket = (unsigned*)(SM + 32768);  // 8 KB
    SmallD* D = (SmallD*)(SM + 40960);

    // ---------------- P0: rank counting (tiles bi x bj x img) ----------
    {
        unsigned* sj = (unsigned*)A;
        if (blk == 0 && t < imgs) pcn[t] = 0;
        const int T0 = RB * RB * imgs;
        for (int vb = blk; vb < T0; vb += GRIDN) {
            const int img = vb / (RB * RB);
            const int rem = vb % (RB * RB);
            const int bi = rem / RB, bj = rem % RB;
            const float* P = proposals + (size_t)img * N * 5;
            __syncthreads();
            {
                int j = bj * BLOCK + t;
                sj[t] = (j < N) ? __float_as_uint(P[j*5 + 4]) : 0u;
            }
            __syncthreads();
            const int i = bi * BLOCK + t;
            if (i < N) {
                const unsigned my = __float_as_uint(P[i*5 + 4]);
                int p = 0;
                const uint4* s4 = (const uint4*)sj;
#pragma unroll
                for (int q = 0; q < BLOCK/4; ++q) {
                    uint4 v = s4[q];
                    int jj = bj * BLOCK + q*4;
                    p += (int)((v.x > my) | ((v.x == my) & (jj + 0 < i)));
                    p += (int)((v.y > my) | ((v.y == my) & (jj + 1 < i)));
                    p += (int)((v.z > my) | ((v.z == my) & (jj + 2 < i)));
                    p += (int)((v.w > my) | ((v.w == my) & (jj + 3 < i)));
                }
                rnk[((size_t)(img*RB + bj))*S2 + i] = p;
            }
        }
    }
    grid.sync();

    // ---------------- P1: scatter to sorted SoA ------------------------
    {
        const int T1 = RB * imgs;
        for (int vb = blk; vb < T1; vb += GRIDN) {
            const int img = vb / RB, bi = vb % RB;
            const int i = bi * BLOCK + t;
            const size_t base = (size_t)img * S2;
            if (i >= N) {
                if (i < S2) {
#pragma unroll
                    for (int a = 0; a < 9; ++a) soa[(size_t)a*stride + base + i] = 0.f;
                    sgt[base + i] = -1;
                }
                continue;
            }
            const float* P = proposals + (size_t)img * N * 5;
            const float* E = pred      + (size_t)img * N * 4;
            const int*   G = gt_inds   + (size_t)img * N;
            const float p0 = P[i*5+0], p1 = P[i*5+1], p2 = P[i*5+2],
                        p3 = P[i*5+3], p4 = P[i*5+4];
            const float q0 = E[i*4+0], q1 = E[i*4+1], q2 = E[i*4+2], q3 = E[i*4+3];
            const int   gv = G[i];
            int p = 0;
#pragma unroll
            for (int b = 0; b < RB; ++b)
                p += rnk[((size_t)(img*RB + b))*S2 + i];
            soa[0*stride + base + p] = p0;
            soa[1*stride + base + p] = p1;
            soa[2*stride + base + p] = p2;
            soa[3*stride + base + p] = p3;
            soa[4*stride + base + p] = p4;
            soa[5*stride + base + p] = q0;
            soa[6*stride + base + p] = q1;
            soa[7*stride + base + p] = q2;
            soa[8*stride + base + p] = q3;
            sgt[base + p] = gv;
        }
    }
    grid.sync();

    // ---------------- P2: sparse suppression pairs (triangular tiles) --
    {
        float (*si)[64] = (float(*)[64])A;
        const int T2 = NTRI * imgs;
        for (int vb = blk; vb < T2; vb += GRIDN) {
            const int img = vb / NTRI;
            const int tri = vb % NTRI;
            int ic = 0;
            while ((ic + 1)*(ic + 2)/2 <= tri) ++ic;
            const int jc = tri - ic*(ic + 1)/2;      // jc <= ic
            const size_t base = (size_t)img * S2;
            __syncthreads();
            for (int idx = t; idx < 512; idx += BLOCK) {
                int f = idx >> 6, e = idx & 63;
                int a = (f < 4) ? f : f + 1;
                si[f][e] = soa[(size_t)a*stride + base + ic*64 + e];
            }
            __syncthreads();
            const int j = jc*64 + lane;
            const float jx1 = soa[0*stride+base+j], jy1 = soa[1*stride+base+j];
            const float jx2 = soa[2*stride+base+j], jy2 = soa[3*stride+base+j];
            const float j0  = soa[5*stride+base+j], j1  = soa[6*stride+base+j];
            const float j2  = soa[7*stride+base+j], j3  = soa[8*stride+base+j];
            const bool jin = (j < N);
            unsigned* PL = prs + (size_t)img * PCAP;
            for (int ii = 0; ii < 16; ++ii) {
                int il = wave*16 + ii;
                int i  = ic*64 + il;
                bool s = false;
                if (jin && i < N && i > j) {
                    float iw = fminf(jx2, si[2][il]) - fmaxf(jx1, si[0][il]);
                    float ih = fminf(jy2, si[3][il]) - fmaxf(jy1, si[1][il]);
                    if (iw > 0.f && ih > 0.f) {
                        float d0 = j0-si[4][il], d1 = j1-si[5][il];
                        float d2 = j2-si[6][il], d3 = j3-si[7][il];
                        float diff = 0.25f*(d0*d0 + d1*d1 + d2*d2 + d3*d3);
                        s = diff < 0.1f;   // TAG_THR
                    }
                }
                unsigned long long m = __ballot(s);
                if (m) {
                    int leader = __ffsll((unsigned long long)m) - 1;
                    int basei = 0;
                    if (lane == leader) basei = atomicAdd(&pcn[img], __popcll(m));
                    basei = __shfl(basei, leader);
                    if (s) {
                        int idx = basei + __popcll(m & ((lane == 0) ? 0ull : (~0ull >> (64 - lane))));
                        if (idx < PCAP) PL[idx] = ((unsigned)j << 11) | (unsigned)i;
                    }
                }
            }
        }
    }
    grid.sync();

    // ---------------- P3: greedy + eff/nsteps (one block per image) ----
    if (blk < imgs) {
        const int img = blk;
        const size_t base = (size_t)img * S2;
        unsigned long long* slocAll = (unsigned long long*)A;   // 16 KB

        int P = pcn[img]; if (P > PCAP) P = PCAP;
        const unsigned* PL = prs + (size_t)img * PCAP;
        const bool staged = (P <= LDSP2);

        for (int x = t; x < S2; x += BLOCK) slocAll[x] = 0ull;
        if (t < NCH) D->bcnt[t] = 0;
        if (t == 0) D->sV = 0;
        __syncthreads();
        if (staged) for (int p = t; p < P; p += BLOCK) spair[p] = PL[p];
        for (int g = wave; g < NCH; g += NWAVES) {
            int j = g*64 + lane;
            int gv = sgt[base + j];
            float a = soa[1*stride + base + j];
            float b = soa[3*stride + base + j];
            bool invalid = !(gv >= 0 && (b - a) > 0.f);
            unsigned long long bb = __ballot(invalid);
            if (lane == 0) {
                D->skilled[g] = bb;
                D->svalid[g] = ~bb;
                atomicAdd(&D->sV, 64 - __popcll(bb));
            }
        }
        __syncthreads();
        for (int p = t; p < P; p += BLOCK) {
            unsigned v = staged ? spair[p] : PL[p];
            int lo = v >> 11, hi = v & 2047;
            if ((lo >> 6) == (hi >> 6)) {
                atomicOr(&slocAll[hi], 1ull << (lo & 63));
            } else {
                int idx = atomicAdd(&D->bcnt[lo >> 6], 1);
                if (idx < BCAP) bucket[(lo >> 6)*BCAP + idx] = v;
            }
        }
        __syncthreads();

        if (wave == 0) {
            const unsigned long long lowmask = (lane == 0) ? 0ull : (~0ull >> (64 - lane));
            for (int c = 0; c < NCH; ++c) {
                unsigned long long U = ~D->skilled[c];
                const unsigned long long loc = slocAll[c*64 + lane];
                unsigned long long sel = 0ull;
                while (U) {
                    bool inU = (U >> lane) & 1ull;
                    unsigned long long Am = __ballot(inU && ((loc & U & lowmask) == 0ull));
                    sel |= Am;
                    bool kill = inU && !((Am >> lane) & 1ull) && ((loc & Am) != 0ull);
                    unsigned long long K = __ballot(kill);
                    U &= ~(Am | K);
                }
                if (lane == 0) D->ssel[c] = sel;
                if (sel != 0ull) {
                    const int bc = D->bcnt[c];
                    if (bc <= BCAP) {
                        for (int q = lane; q < bc; q += 64) {
                            unsigned v = bucket[c*BCAP + q];
                            int lo = v >> 11, hi = v & 2047;
                            if ((sel >> (lo & 63)) & 1ull)
                                atomicOr(&D->skilled[hi >> 6], 1ull << (hi & 63));
                        }
                    } else {
                        for (int p = lane; p < P; p += 64) {
                            unsigned v = PL[p];
                            int lo = v >> 11, hi = v & 2047;
                            if ((lo >> 6) == c && (hi >> 6) != c &&
                                ((sel >> (lo & 63)) & 1ull))
                                atomicOr(&D->skilled[hi >> 6], 1ull << (hi & 63));
                        }
                    }
                }
            }
        }
        __syncthreads();
        if (t < NW) selw[(size_t)img*NW + t] = D->ssel[t];

        // ---- effsteps part (reuse region A as sistar + hist) ----
        int* sistar = (int*)A;                   // 8 KB
        unsigned* hist = (unsigned*)(A + 8192);  // 8 KB
        for (int x = t; x < S2; x += BLOCK) { sistar[x] = EFF_INF; hist[x] = 0u; }
        if (t == 0) {
            int s = 0;
            for (int w = 0; w < NW; ++w) { D->pfx[w] = s; s += __popcll(D->ssel[w]); }
            D->pfx[NW] = s;
        }
        __syncthreads();
        for (int p = t; p < P; p += BLOCK) {
            unsigned v = staged ? spair[p] : PL[p];
            int lo = v >> 11, hi = v & 2047;
            if ((D->ssel[lo >> 6] >> (lo & 63)) & 1ull) atomicMin(&sistar[hi], lo);
        }
        __syncthreads();
#pragma unroll
        for (int k = 0; k < 8; ++k) {
            const int j = k*BLOCK + t;
            const int jw = j >> 6, jb = j & 63;
            bool valid = (D->svalid[jw] >> jb) & 1ull;
            bool selb  = (D->ssel[jw] >> jb) & 1ull;
            int e;
            if (!valid) e = 0;
            else if (selb)
                e = D->pfx[jw] + __popcll(D->ssel[jw] & (jb ? (~0ull >> (64 - jb)) : 0ull));
            else {
                int is = sistar[j];
                if (is == EFF_INF) e = EFF_INF;
                else {
                    int iw_ = is >> 6, ib = is & 63;
                    e = D->pfx[iw_] + __popcll(D->ssel[iw_] & (ib ? (~0ull >> (64 - ib)) : 0ull)) + 1;
                    atomicAdd(&hist[e - 1], 1u);
                }
            }
            eff[(size_t)img*S2 + j] = e;
        }
        __syncthreads();

        const int V = D->sV, Sc = D->pfx[NW];
        unsigned loc8[8]; unsigned s = 0;
#pragma unroll
        for (int k = 0; k < 8; ++k) { s += hist[t*8 + k]; loc8[k] = s; }
        unsigned tot = s;
        for (int o = 1; o < 64; o <<= 1) {
            unsigned u = __shfl_up(tot, o);
            if (lane >= o) tot += u;
        }
        if (lane == 63) D->wsum[wave] = tot;
        __syncthreads();
        unsigned woff = 0;
        for (int w = 0; w < wave; ++w) woff += D->wsum[w];
        unsigned exclP = woff + tot - s;
        __syncthreads();
#pragma unroll
        for (int k = 0; k < 8; ++k) hist[t*8 + k] = exclP + loc8[k];
        __syncthreads();
        int best = EFF_INF;
        for (int r = t; r < Sc; r += BLOCK) {
            unsigned rem = (r == 0) ? 0u : hist[r - 1];
            int alive = V - r - (int)rem;
            if (alive < 2) best = min(best, r);
        }
        for (int o = 32; o > 0; o >>= 1) best = min(best, __shfl_down(best, o));
        if (lane == 0) D->bm[wave] = best;
        __syncthreads();
        if (t == 0) {
            int b = D->bm[0];
            for (int w = 1; w < NWAVES; ++w) b = min(b, D->bm[w]);
            nst[img] = min(b, Sc);
        }
    }
    grid.sync();

    // ---------------- P4: pair sums (virtual blocks ic x img) ----------
    {
        const int T4 = PB * imgs;
        for (int vb = blk; vb < T4; vb += GRIDN) {
            const int img = vb / PB, ic = vb % PB;
            const size_t base = (size_t)img * S2;
            __syncthreads();
            if (t < NW) D->ssel[t] = selw[(size_t)img*NW + t];
            if (t == 0) D->anyact = 0;
            __syncthreads();
            if (t == 0) {
                int s = 0;
                for (int w = 0; w < NW; ++w) { D->pfx[w] = s; s += __popcll(D->ssel[w]); }
                D->pfx[NW] = s;
            }
            __syncthreads();
            const int ns = nst[img];
            float bx1[4], by1[4], bx2[4], by2[4], f0[4], f1[4], f2[4], f3[4];
            int bgt[4], rk[4]; bool act[4];
            bool any = false;
#pragma unroll
            for (int u = 0; u < 4; ++u) {
                const int i = ic*SPB + wave*4 + u;
                const int iw_ = i >> 6, ib = i & 63;
                bool selb = (D->ssel[iw_] >> ib) & 1ull;
                int r = D->pfx[iw_] + __popcll(D->ssel[iw_] & (ib ? (~0ull >> (64 - ib)) : 0ull));
                rk[u] = r;
                act[u] = selb && (r < ns);
                any |= act[u];
                if (act[u]) {
                    bx1[u] = soa[0*stride+base+i]; by1[u] = soa[1*stride+base+i];
                    bx2[u] = soa[2*stride+base+i]; by2[u] = soa[3*stride+base+i];
                    f0[u]  = soa[5*stride+base+i]; f1[u]  = soa[6*stride+base+i];
                    f2[u]  = soa[7*stride+base+i]; f3[u]  = soa[8*stride+base+i];
                    bgt[u] = sgt[base + i];
                } else {
                    bx1[u]=by1[u]=bx2[u]=by2[u]=0.f; f0[u]=f1[u]=f2[u]=f3[u]=0.f; bgt[u]=-2;
                }
            }
            if (any && lane == 0) D->anyact = 1;
            __syncthreads();

            float sPull = 0.f, cPull = 0.f, sPush = 0.f, cPush = 0.f;
            if (D->anyact) {
                float ps[4] = {0,0,0,0}, pn[4] = {0,0,0,0};
                float qs[4] = {0,0,0,0}, qn[4] = {0,0,0,0};
                for (int jt = 0; jt < NCH; ++jt) {
                    const int j = jt*64 + lane;
                    const float jx1 = soa[0*stride+base+j], jy1 = soa[1*stride+base+j];
                    const float jx2 = soa[2*stride+base+j], jy2 = soa[3*stride+base+j];
                    const float jsc = soa[4*stride+base+j];
                    const float j0  = soa[5*stride+base+j], j1  = soa[6*stride+base+j];
                    const float j2  = soa[7*stride+base+j], j3  = soa[8*stride+base+j];
                    const int   jgt = sgt[base + j];
                    const int   jef = eff[(size_t)img*S2 + j];
#pragma unroll
                    for (int u = 0; u < 4; ++u) {
                        if (!act[u]) continue;            // wave-uniform
                        if (rk[u] < jef) {
                            float iw = fminf(jx2, bx2[u]) - fmaxf(jx1, bx1[u]);
                            float ih = fminf(jy2, by2[u]) - fmaxf(jy1, by1[u]);
                            if (iw > 0.f && ih > 0.f) {
                                float d0 = j0 - f0[u], d1 = j1 - f1[u];
                                float d2 = j2 - f2[u], d3 = j3 - f3[u];
                                float diff = 0.25f*(d0*d0 + d1*d1 + d2*d2 + d3*d3);
                                bool check = diff < 0.1f;
                                bool same  = (jgt == bgt[u]);
                                if (same && !check)      { ps[u] += diff * jsc;       pn[u] += 1.f; }
                                else if (!same && check) { qs[u] += expf(-diff)*jsc;  qn[u] += 1.f; }
                            }
                        }
                    }
                }
#pragma unroll
                for (int u = 0; u < 4; ++u) {
                    if (!act[u]) continue;                // wave-uniform
                    float a0 = ps[u], a1 = pn[u], a2 = qs[u], a3 = qn[u];
                    for (int o = 32; o > 0; o >>= 1) {
                        a0 += __shfl_down(a0, o); a1 += __shfl_down(a1, o);
                        a2 += __shfl_down(a2, o); a3 += __shfl_down(a3, o);
                    }
                    if (lane == 0) {
                        if (a1 > 0.f) { sPull += a0 / a1; cPull += 1.f; }
                        if (a3 > 0.f) { sPush += a2 / a3; cPush += 1.f; }
                    }
                }
            }
            if (lane == 0) {
                D->pw[wave][0] = sPull; D->pw[wave][1] = cPull;
                D->pw[wave][2] = sPush; D->pw[wave][3] = cPush;
            }
            __syncthreads();
            if (t == 0) {
                float a = 0, b = 0, c = 0, d = 0;
                for (int w = 0; w < NWAVES; ++w) {
                    a += D->pw[w][0]; b += D->pw[w][1];
                    c += D->pw[w][2]; d += D->pw[w][3];
                }
                float* p = par + (size_t)vb * 4;
                p[0] = a; p[1] = b; p[2] = c; p[3] = d;
            }
        }
    }
    grid.sync();

    // ---------------- P5: finalize --------------------------------------
    if (blk == 0) {
        float (*a)[4] = (float(*)[4])A;    // [8][4]
        if (t < 32) ((float*)a)[t] = 0.f;
        __syncthreads();
        for (int e = t; e < imgs * PB; e += BLOCK) {
            int img = e / PB;
            const float* p = par + (size_t)e * 4;
#pragma unroll
            for (int k = 0; k < 4; ++k) {
                float v = p[k];
                if (v != 0.f) atomicAdd(&a[img][k], v);
            }
        }
        __syncthreads();
        if (t == 0) {
            float push = 0.f, pull = 0.f;
            for (int i = 0; i < imgs; ++i) {
                pull += a[i][0] / (a[i][1] + 1e-6f);
                push += a[i][2] / (a[i][3] + 1e-6f);
            }
            out[0] = push / (float)imgs;   // push_loss
            out[1] = pull / (float)imgs;   // pull_loss
        }
    }
}

// =====================================================================
// FALLBACK PATH (R1 kernel) — only if ws too small / N > 2048 / imgs > 8.
// =====================================================================
__global__ __launch_bounds__(BLOCK) void tagloss_kernel(
    const float* __restrict__ pred, const int* __restrict__ gt_inds,
    const float* __restrict__ proposals, float* __restrict__ ws, int N)
{
    const int img = blockIdx.x, t = threadIdx.x;
    const int lane = t & 63, wav = t >> 6;
    const float* P = proposals + (size_t)img * N * 5;
    const float* E = pred      + (size_t)img * N * 4;
    const int*   G = gt_inds   + (size_t)img * N;
    float x1[KMAX], y1[KMAX], x2[KMAX], y2[KMAX], sc[KMAX];
    float e0[KMAX], e1[KMAX], e2[KMAX], e3[KMAX];
    int gt[KMAX]; unsigned amask = 0u; int local_alive = 0;
#pragma unroll
    for (int k = 0; k < KMAX; ++k) {
        int j = k * BLOCK + t;
        if (j < N) {
            x1[k]=P[j*5+0]; y1[k]=P[j*5+1]; x2[k]=P[j*5+2]; y2[k]=P[j*5+3]; sc[k]=P[j*5+4];
            e0[k]=E[j*4+0]; e1[k]=E[j*4+1]; e2[k]=E[j*4+2]; e3[k]=E[j*4+3]; gt[k]=G[j];
            if (gt[k] >= 0 && (y2[k]-y1[k]) > 0.0f) { amask |= 1u<<k; local_alive++; }
        } else { x1[k]=y1[k]=x2[k]=y2[k]=0.f; sc[k]=0.f; e0[k]=e1[k]=e2[k]=e3[k]=0.f; gt[k]=-1; }
    }
    __shared__ unsigned long long s_key[NWAVES];
    __shared__ float s_b[9];
    __shared__ float s_part[NWAVES][5];
    int alive_count;
    {
        float v = (float)local_alive;
#pragma unroll
        for (int o = 32; o > 0; o >>= 1) v += __shfl_down(v, o);
        if (lane == 0) s_part[wav][0] = v;
        __syncthreads();
        float tot = 0.f;
        for (int w = 0; w < NWAVES; ++w) tot += s_part[w][0];
        alive_count = (int)tot;
    }
    float tot_pull=0.f, tot_push=0.f, pull_cnt=0.f, push_cnt=0.f;
    while (alive_count >= 2) {
        unsigned long long key = 0ull;
#pragma unroll
        for (int k = 0; k < KMAX; ++k)
            if (amask & (1u<<k)) {
                unsigned long long kk = ((unsigned long long)__float_as_uint(sc[k])<<32)
                                      | (unsigned long long)(0xFFFFFFFFu - (unsigned)(k*BLOCK+t));
                if (kk > key) key = kk;
            }
#pragma unroll
        for (int o = 32; o > 0; o >>= 1) {
            unsigned long long ok = __shfl_down(key, o);
            if (ok > key) key = ok;
        }
        if (lane == 0) s_key[wav] = key;
        __syncthreads();
        unsigned long long bk = s_key[0];
        for (int w = 1; w < NWAVES; ++w) if (s_key[w] > bk) bk = s_key[w];
        const int i = (int)(0xFFFFFFFFu - (unsigned)(bk & 0xFFFFFFFFull));
        if ((i & (BLOCK-1)) == t) {
            int k = i / BLOCK;
            s_b[0]=x1[k]; s_b[1]=y1[k]; s_b[2]=x2[k]; s_b[3]=y2[k];
            s_b[4]=e0[k]; s_b[5]=e1[k]; s_b[6]=e2[k]; s_b[7]=e3[k];
            s_b[8]=__int_as_float(gt[k]);
        }
        __syncthreads();
        const float bx1=s_b[0], by1=s_b[1], bx2=s_b[2], by2=s_b[3];
        const float f0=s_b[4], f1=s_b[5], f2=s_b[6], f3=s_b[7];
        const int bgt = __float_as_int(s_b[8]);
        const float areai = (bx2-bx1)*(by2-by1);
        float psum=0.f,qsum=0.f,pn=0.f,qn=0.f,scnt=0.f;
#pragma unroll
        for (int k = 0; k < KMAX; ++k) {
            if (!(amask & (1u<<k))) continue;
            int j = k*BLOCK+t;
            if (j == i) { amask &= ~(1u<<k); continue; }
            float iw = fmaxf(fminf(x2[k],bx2)-fmaxf(x1[k],bx1),0.f);
            float ih = fmaxf(fminf(y2[k],by2)-fmaxf(y1[k],by1),0.f);
            float inter = iw*ih;
            float uni = (x2[k]-x1[k])*(y2[k]-y1[k]) + areai - inter;
            float iou = inter / fmaxf(uni, 1e-12f);
            if (iou > 0.f) {
                float d0=e0[k]-f0,d1=e1[k]-f1,d2=e2[k]-f2,d3=e3[k]-f3;
                float diff = 0.25f*(d0*d0+d1*d1+d2*d2+d3*d3);
                bool check = diff < 0.1f;
                bool same = (gt[k]==bgt);
                if (same && !check) { psum += diff*sc[k]; pn += 1.f; }
                if (!same && check) { qsum += __expf(-diff)*sc[k]; qn += 1.f; }
                if (check)          { amask &= ~(1u<<k); scnt += 1.f; }
            }
        }
        float r0=psum,r1=pn,r2=qsum,r3=qn,r4=scnt;
#pragma unroll
        for (int o = 32; o > 0; o >>= 1) {
            r0+=__shfl_down(r0,o); r1+=__shfl_down(r1,o); r2+=__shfl_down(r2,o);
            r3+=__shfl_down(r3,o); r4+=__shfl_down(r4,o);
        }
        if (lane == 0) { s_part[wav][0]=r0;s_part[wav][1]=r1;s_part[wav][2]=r2;s_part[wav][3]=r3;s_part[wav][4]=r4; }
        __syncthreads();
        float T0=0,T1=0,T2=0,T3=0,T4=0;
        for (int w = 0; w < NWAVES; ++w) {
            T0+=s_part[w][0];T1+=s_part[w][1];T2+=s_part[w][2];T3+=s_part[w][3];T4+=s_part[w][4];
        }
        if (T1 > 0.f) { tot_pull += T0/T1; pull_cnt += 1.f; }
        if (T3 > 0.f) { tot_push += T2/T3; push_cnt += 1.f; }
        alive_count -= 1 + (int)T4;
    }
    if (t == 0) {
        ws[img*2+0] = tot_push / (push_cnt + 1e-6f);
        ws[img*2+1] = tot_pull / (pull_cnt + 1e-6f);
    }
}

__global__ void finalize_fb_kernel(const float* __restrict__ ws,
                                   float* __restrict__ out, int imgs)
{
    if (threadIdx.x == 0 && blockIdx.x == 0) {
        float push = 0.f, pull = 0.f;
        for (int k = 0; k < imgs; ++k) { push += ws[2*k]; pull += ws[2*k+1]; }
        out[0] = push / (float)imgs;
        out[1] = pull / (float)imgs;
    }
}

// =====================================================================
extern "C" void kernel_launch(void* const* d_in, const int* in_sizes, int n_in,
                              void* d_out, int out_size, void* d_ws, size_t ws_size,
                              hipStream_t stream) {
    const float* pred      = (const float*)d_in[0];
    const int*   gt_inds   = (const int*)  d_in[1];
    const float* proposals = (const float*)d_in[2];
    const int imgs = in_sizes[3] / 80;     // gt_bboxes (IMGS,20,4)
    const int N    = in_sizes[1] / imgs;   // gt_inds (IMGS,N)

    size_t off = 0;
    auto alloc = [&](size_t b) { size_t o = off; off += (b + 255) & ~(size_t)255; return o; };
    const size_t soa_off  = alloc((size_t)9 * imgs * S2 * 4);
    const size_t sgt_off  = alloc((size_t)imgs * S2 * 4);
    const size_t sel_off  = alloc((size_t)imgs * NW * 8);
    const size_t eff_off  = alloc((size_t)imgs * S2 * 4);
    const size_t nst_off  = alloc((size_t)imgs * 4);
    const size_t par_off  = alloc((size_t)imgs * PB * 16);
    const size_t rnk_off  = alloc((size_t)imgs * RB * S2 * 4);
    const size_t prs_off  = alloc((size_t)imgs * PCAP * 4);
    const size_t pcn_off  = alloc((size_t)imgs * 4);
    const size_t need = off;

    if (N <= S2 && imgs <= 8 && ws_size >= need) {
        char* w = (char*)d_ws;
        float*              soa  = (float*)(w + soa_off);
        int*                sgt  = (int*)(w + sgt_off);
        unsigned long long* sel  = (unsigned long long*)(w + sel_off);
        int*                eff  = (int*)(w + eff_off);
        int*                nst  = (int*)(w + nst_off);
        float*              par  = (float*)(w + par_off);
        int*                rnk  = (int*)(w + rnk_off);
        unsigned*           prs  = (unsigned*)(w + prs_off);
        int*                pcn  = (int*)(w + pcn_off);
        float*              outp = (float*)d_out;
        int nN = N, nimgs = imgs;

        void* args[] = {
            (void*)&pred, (void*)&gt_inds, (void*)&proposals,
            (void*)&soa, (void*)&sgt, (void*)&rnk, (void*)&prs, (void*)&pcn,
            (void*)&sel, (void*)&eff, (void*)&nst, (void*)&par, (void*)&outp,
            (void*)&nN, (void*)&nimgs
        };
        hipLaunchCooperativeKernel((const void*)mega_kernel,
                                   dim3(GRIDN), dim3(BLOCK), args, 0, stream);
    } else {
        float* ws = (float*)d_ws;
        tagloss_kernel<<<imgs, BLOCK, 0, stream>>>(pred, gt_inds, proposals, ws, N);
        finalize_fb_kernel<<<1, 64, 0, stream>>>(ws, (float*)d_out, imgs);
    }
}

// Round 15
// 152.533 us; speedup vs baseline: 2.0131x; 2.0131x over previous
//
#include <hip/hip_runtime.h>
#include <stdint.h>

#define BLOCK 256
#define KMAX 8
#define NWAVES (BLOCK / 64)
#define S2 2048          // padded N (pow2); N=2000 fits (11-bit indices)
#define NW 32            // 64-bit words per selection mask
#define NCH 32           // 64-element chunks
#define SPB 16           // selector slots per pairs-block
#define PB (S2 / SPB)    // pairs blocks per image (128)
#define RB (S2 / BLOCK)  // rank tiles per axis (8)
#define PCAP 65536       // max suppression pairs per image (measured ~300)
#define LDSP2 4096       // pairs staged in LDS if P <= this (16 KB)
#define BCAP 64          // cross-chunk bucket capacity (expected ~9/chunk)
#define EFF_INF 0x7FFFFFFF

// =====================================================================
// K1a: rank counting (tiles bi x bj x img). Also zeroes pair counters,
// the pairs-final accumulator and the completion ticket (stream order
// makes these visible to later kernels).
// =====================================================================
__global__ __launch_bounds__(BLOCK) void rankcount_kernel(
    const float* __restrict__ proposals,
    int* __restrict__ partial, int* __restrict__ pcnt,
    float* __restrict__ acc, int* __restrict__ done, int N, int imgs)
{
    const int bi = blockIdx.x, bj = blockIdx.y, img = blockIdx.z;
    const int t = threadIdx.x;
    if (bi == 0 && bj == 0 && img == 0) {
        if (t < imgs) pcnt[t] = 0;
        if (t >= 64 && t < 64 + imgs*4) acc[t - 64] = 0.f;
        if (t == 128) *done = 0;
    }
    const float* P = proposals + (size_t)img * N * 5;
    __shared__ unsigned sj[BLOCK];
    const int jbase = bj * BLOCK;
    {
        int j = jbase + t;
        sj[t] = (j < N) ? __float_as_uint(P[j*5 + 4]) : 0u;
    }
    __syncthreads();
    const int i = bi * BLOCK + t;
    if (i >= N) return;
    const unsigned my = __float_as_uint(P[i*5 + 4]);
    int p = 0;
    const uint4* s4 = (const uint4*)sj;
#pragma unroll
    for (int q = 0; q < BLOCK/4; ++q) {
        uint4 v = s4[q];
        int jj = jbase + q*4;
        p += (int)((v.x > my) | ((v.x == my) & (jj + 0 < i)));
        p += (int)((v.y > my) | ((v.y == my) & (jj + 1 < i)));
        p += (int)((v.z > my) | ((v.z == my) & (jj + 2 < i)));
        p += (int)((v.w > my) | ((v.w == my) & (jj + 3 < i)));
    }
    partial[((size_t)(img*RB + bj))*S2 + i] = p;
}

// =====================================================================
// K1b: sum partials -> position; gather payload; scatter to sorted SoA.
// =====================================================================
__global__ __launch_bounds__(BLOCK) void rankscatter_kernel(
    const float* __restrict__ pred, const int* __restrict__ gt_inds,
    const float* __restrict__ proposals, const int* __restrict__ partial,
    float* __restrict__ soa, int* __restrict__ sgt, int N, int imgs)
{
    const int img = blockIdx.y, t = threadIdx.x;
    const int i = blockIdx.x * BLOCK + t;
    const size_t stride = (size_t)imgs * S2;
    const size_t base   = (size_t)img * S2;

    if (i >= N) {
        if (i < S2) {
#pragma unroll
            for (int a = 0; a < 9; ++a) soa[(size_t)a*stride + base + i] = 0.f;
            sgt[base + i] = -1;
        }
        return;
    }

    const float* P = proposals + (size_t)img * N * 5;
    const float* E = pred      + (size_t)img * N * 4;
    const int*   G = gt_inds   + (size_t)img * N;

    const float p0 = P[i*5+0], p1 = P[i*5+1], p2 = P[i*5+2],
                p3 = P[i*5+3], p4 = P[i*5+4];
    const float q0 = E[i*4+0], q1 = E[i*4+1], q2 = E[i*4+2], q3 = E[i*4+3];
    const int   gg = G[i];

    int p = 0;
#pragma unroll
    for (int b = 0; b < RB; ++b)
        p += partial[((size_t)(img*RB + b))*S2 + i];

    soa[0*stride + base + p] = p0;
    soa[1*stride + base + p] = p1;
    soa[2*stride + base + p] = p2;
    soa[3*stride + base + p] = p3;
    soa[4*stride + base + p] = p4;
    soa[5*stride + base + p] = q0;
    soa[6*stride + base + p] = q1;
    soa[7*stride + base + p] = q2;
    soa[8*stride + base + p] = q3;
    sgt[base + p] = gg;
}

// =====================================================================
// K2: SPARSE suppression pairs, packed (lo<<11|hi), lo<hi.
// =====================================================================
__global__ __launch_bounds__(BLOCK) void suppairs_kernel(
    const float* __restrict__ soa, unsigned* __restrict__ pairs,
    int* __restrict__ pcnt, int N, int imgs)
{
    const int ic = blockIdx.x, jc = blockIdx.y, img = blockIdx.z;
    if (ic < jc) return;                 // i>j never holds there
    const int t = threadIdx.x, wave = t >> 6, lane = t & 63;
    const size_t stride = (size_t)imgs * S2, base = (size_t)img * S2;
    __shared__ float si[8][64];
    for (int idx = t; idx < 512; idx += BLOCK) {
        int f = idx >> 6, e = idx & 63;
        int a = (f < 4) ? f : f + 1;     // arrays {0,1,2,3,5,6,7,8}
        si[f][e] = soa[(size_t)a*stride + base + ic*64 + e];
    }
    __syncthreads();
    const int j = jc*64 + lane;
    const float jx1 = soa[0*stride+base+j], jy1 = soa[1*stride+base+j];
    const float jx2 = soa[2*stride+base+j], jy2 = soa[3*stride+base+j];
    const float j0  = soa[5*stride+base+j], j1  = soa[6*stride+base+j];
    const float j2  = soa[7*stride+base+j], j3  = soa[8*stride+base+j];
    const bool jin = (j < N);
    unsigned* PL = pairs + (size_t)img * PCAP;
    for (int ii = 0; ii < 16; ++ii) {
        int il = wave*16 + ii;
        int i  = ic*64 + il;
        bool s = false;
        if (jin && i < N && i > j) {
            float iw = fminf(jx2, si[2][il]) - fmaxf(jx1, si[0][il]);
            float ih = fminf(jy2, si[3][il]) - fmaxf(jy1, si[1][il]);
            if (iw > 0.f && ih > 0.f) {
                float d0 = j0-si[4][il], d1 = j1-si[5][il];
                float d2 = j2-si[6][il], d3 = j3-si[7][il];
                float diff = 0.25f*(d0*d0 + d1*d1 + d2*d2 + d3*d3);
                s = diff < 0.1f;   // TAG_THR
            }
        }
        unsigned long long m = __ballot(s);
        if (m) {
            int leader = __ffsll((unsigned long long)m) - 1;
            int basei = 0;
            if (lane == leader) basei = atomicAdd(&pcnt[img], __popcll(m));
            basei = __shfl(basei, leader);
            if (s) {
                int idx = basei + __popcll(m & ((lane == 0) ? 0ull : (~0ull >> (64 - lane))));
                if (idx < PCAP) PL[idx] = ((unsigned)j << 11) | (unsigned)i;  // lo=j, hi=i
            }
        }
    }
}

// =====================================================================
// K3: fused greedy + eff/nsteps. One 256-thread block per image.
// Greedy: single pass over pair list (in-chunk -> slocAll bitmask,
// cross-chunk -> per-lo-chunk buckets), then pure-LDS ballot resolve on
// wave 0. Eff: istar[hi] = min selected lo; ranks via prefix popcount.
// (Logic identical to R14's P3, which passed correctness.)
// =====================================================================
__global__ __launch_bounds__(BLOCK) void greedyeff_kernel(
    const unsigned* __restrict__ pairs, const int* __restrict__ pcnt,
    const int* __restrict__ sgt, const float* __restrict__ soa,
    unsigned long long* __restrict__ selw, int* __restrict__ eff,
    int* __restrict__ nsteps, int imgs)
{
    const int img = blockIdx.x, t = threadIdx.x;
    const int lane = t & 63, wave = t >> 6;
    const size_t stride = (size_t)imgs * S2, base = (size_t)img * S2;

    __shared__ __align__(16) char A[16384];          // slocAll | sistar+hist
    __shared__ unsigned spair[LDSP2];                // 16 KB
    __shared__ unsigned bucket[NCH * BCAP];          // 8 KB
    __shared__ int bcnt[NCH];
    __shared__ unsigned long long skilled[NW], ssel[NW], svalid[NW];
    __shared__ int pfx[NW + 1];
    __shared__ unsigned wsum[NWAVES];
    __shared__ int bm[NWAVES];
    __shared__ int sV;

    unsigned long long* slocAll = (unsigned long long*)A;

    int P = pcnt[img]; if (P > PCAP) P = PCAP;
    const unsigned* PL = pairs + (size_t)img * PCAP;
    const bool staged = (P <= LDSP2);

    for (int x = t; x < S2; x += BLOCK) slocAll[x] = 0ull;
    if (t < NCH) bcnt[t] = 0;
    if (t == 0) sV = 0;
    __syncthreads();
    if (staged) for (int p = t; p < P; p += BLOCK) spair[p] = PL[p];
    for (int g = wave; g < NCH; g += NWAVES) {
        int j = g*64 + lane;
        int gv = sgt[base + j];
        float a = soa[1*stride + base + j];
        float b = soa[3*stride + base + j];
        bool invalid = !(gv >= 0 && (b - a) > 0.f);
        unsigned long long bb = __ballot(invalid);
        if (lane == 0) {
            skilled[g] = bb;
            svalid[g] = ~bb;
            atomicAdd(&sV, 64 - __popcll(bb));
        }
    }
    __syncthreads();
    for (int p = t; p < P; p += BLOCK) {
        unsigned v = staged ? spair[p] : PL[p];
        int lo = v >> 11, hi = v & 2047;
        if ((lo >> 6) == (hi >> 6)) {
            atomicOr(&slocAll[hi], 1ull << (lo & 63));
        } else {
            int idx = atomicAdd(&bcnt[lo >> 6], 1);
            if (idx < BCAP) bucket[(lo >> 6)*BCAP + idx] = v;
        }
    }
    __syncthreads();

    if (wave == 0) {
        const unsigned long long lowmask = (lane == 0) ? 0ull : (~0ull >> (64 - lane));
        for (int c = 0; c < NCH; ++c) {
            unsigned long long U = ~skilled[c];
            const unsigned long long loc = slocAll[c*64 + lane];
            unsigned long long sel = 0ull;
            while (U) {
                bool inU = (U >> lane) & 1ull;
                unsigned long long Am = __ballot(inU && ((loc & U & lowmask) == 0ull));
                sel |= Am;
                bool kill = inU && !((Am >> lane) & 1ull) && ((loc & Am) != 0ull);
                unsigned long long K = __ballot(kill);
                U &= ~(Am | K);
            }
            if (lane == 0) ssel[c] = sel;
            if (sel != 0ull) {
                const int bc = bcnt[c];
                if (bc <= BCAP) {
                    for (int q = lane; q < bc; q += 64) {
                        unsigned v = bucket[c*BCAP + q];
                        int lo = v >> 11, hi = v & 2047;
                        if ((sel >> (lo & 63)) & 1ull)
                            atomicOr(&skilled[hi >> 6], 1ull << (hi & 63));
                    }
                } else {
                    for (int p = lane; p < P; p += 64) {
                        unsigned v = PL[p];
                        int lo = v >> 11, hi = v & 2047;
                        if ((lo >> 6) == c && (hi >> 6) != c &&
                            ((sel >> (lo & 63)) & 1ull))
                            atomicOr(&skilled[hi >> 6], 1ull << (hi & 63));
                    }
                }
            }
        }
    }
    __syncthreads();
    if (t < NW) selw[(size_t)img*NW + t] = ssel[t];

    // ---- eff/nsteps (reuse A as sistar + hist) ----
    int* sistar = (int*)A;                   // 8 KB
    unsigned* hist = (unsigned*)(A + 8192);  // 8 KB
    for (int x = t; x < S2; x += BLOCK) { sistar[x] = EFF_INF; hist[x] = 0u; }
    if (t == 0) {
        int s = 0;
        for (int w = 0; w < NW; ++w) { pfx[w] = s; s += __popcll(ssel[w]); }
        pfx[NW] = s;
    }
    __syncthreads();
    for (int p = t; p < P; p += BLOCK) {
        unsigned v = staged ? spair[p] : PL[p];
        int lo = v >> 11, hi = v & 2047;
        if ((ssel[lo >> 6] >> (lo & 63)) & 1ull) atomicMin(&sistar[hi], lo);
    }
    __syncthreads();
#pragma unroll
    for (int k = 0; k < 8; ++k) {
        const int j = k*BLOCK + t;
        const int jw = j >> 6, jb = j & 63;
        bool valid = (svalid[jw] >> jb) & 1ull;
        bool selb  = (ssel[jw] >> jb) & 1ull;
        int e;
        if (!valid) e = 0;
        else if (selb)
            e = pfx[jw] + __popcll(ssel[jw] & (jb ? (~0ull >> (64 - jb)) : 0ull));
        else {
            int is = sistar[j];
            if (is == EFF_INF) e = EFF_INF;
            else {
                int iw_ = is >> 6, ib = is & 63;
                e = pfx[iw_] + __popcll(ssel[iw_] & (ib ? (~0ull >> (64 - ib)) : 0ull)) + 1;
                atomicAdd(&hist[e - 1], 1u);
            }
        }
        eff[(size_t)img*S2 + j] = e;
    }
    __syncthreads();

    const int V = sV, Sc = pfx[NW];
    unsigned loc8[8]; unsigned s = 0;
#pragma unroll
    for (int k = 0; k < 8; ++k) { s += hist[t*8 + k]; loc8[k] = s; }
    unsigned tot = s;
    for (int o = 1; o < 64; o <<= 1) {
        unsigned u = __shfl_up(tot, o);
        if (lane >= o) tot += u;
    }
    if (lane == 63) wsum[wave] = tot;
    __syncthreads();
    unsigned woff = 0;
    for (int w = 0; w < wave; ++w) woff += wsum[w];
    unsigned exclP = woff + tot - s;
    __syncthreads();
#pragma unroll
    for (int k = 0; k < 8; ++k) hist[t*8 + k] = exclP + loc8[k];
    __syncthreads();
    int best = EFF_INF;
    for (int r = t; r < Sc; r += BLOCK) {
        unsigned rem = (r == 0) ? 0u : hist[r - 1];
        int alive = V - r - (int)rem;
        if (alive < 2) best = min(best, r);
    }
    for (int o = 32; o > 0; o >>= 1) best = min(best, __shfl_down(best, o));
    if (lane == 0) bm[wave] = best;
    __syncthreads();
    if (t == 0) {
        int b = bm[0];
        for (int w = 1; w < NWAVES; ++w) b = min(b, bm[w]);
        nsteps[img] = min(b, Sc);
    }
}

// =====================================================================
// K4: pair sums fused with finalize. Per-block 4 partials -> device-scope
// atomicAdd into acc[img]; last block (ticket) computes out[2].
// =====================================================================
__global__ __launch_bounds__(BLOCK) void pairsfinal_kernel(
    const float* __restrict__ soa, const int* __restrict__ sgt,
    const int* __restrict__ eff, const unsigned long long* __restrict__ selw,
    const int* __restrict__ nsteps, float* __restrict__ acc,
    int* __restrict__ done, float* __restrict__ out, int imgs)
{
    const int ic = blockIdx.x, img = blockIdx.y;
    const int t = threadIdx.x, wave = t >> 6, lane = t & 63;
    const size_t stride = (size_t)imgs * S2, base = (size_t)img * S2;
    __shared__ unsigned long long ss[NW];
    __shared__ float pw[NWAVES][4];
    __shared__ int anyact, ticket;
    if (t < NW) ss[t] = selw[(size_t)img*NW + t];
    if (t == 0) anyact = 0;
    __syncthreads();
    const int ns = nsteps[img];

    float bx1[4], by1[4], bx2[4], by2[4], f0[4], f1[4], f2[4], f3[4];
    int bgt[4], rk[4]; bool act[4];
    bool any = false;
#pragma unroll
    for (int u = 0; u < 4; ++u) {
        const int i = ic*SPB + wave*4 + u;
        const int iw_ = i >> 6, ib = i & 63;
        bool selb = (ss[iw_] >> ib) & 1ull;
        int r = __popcll(ss[iw_] & (ib ? (~0ull >> (64 - ib)) : 0ull));
        for (int w = 0; w < iw_; ++w) r += __popcll(ss[w]);
        rk[u] = r;
        act[u] = selb && (r < ns);
        any |= act[u];
        if (act[u]) {
            bx1[u] = soa[0*stride+base+i]; by1[u] = soa[1*stride+base+i];
            bx2[u] = soa[2*stride+base+i]; by2[u] = soa[3*stride+base+i];
            f0[u]  = soa[5*stride+base+i]; f1[u]  = soa[6*stride+base+i];
            f2[u]  = soa[7*stride+base+i]; f3[u]  = soa[8*stride+base+i];
            bgt[u] = sgt[base + i];
        } else {
            bx1[u]=by1[u]=bx2[u]=by2[u]=0.f; f0[u]=f1[u]=f2[u]=f3[u]=0.f; bgt[u]=-2;
        }
    }
    if (any && lane == 0) anyact = 1;   // benign same-value race
    __syncthreads();

    if (anyact) {
        float ps[4] = {0,0,0,0}, pn[4] = {0,0,0,0};
        float qs[4] = {0,0,0,0}, qn[4] = {0,0,0,0};
        for (int jt = 0; jt < NCH; ++jt) {
            const int j = jt*64 + lane;
            const float jx1 = soa[0*stride+base+j], jy1 = soa[1*stride+base+j];
            const float jx2 = soa[2*stride+base+j], jy2 = soa[3*stride+base+j];
            const float jsc = soa[4*stride+base+j];
            const float j0  = soa[5*stride+base+j], j1  = soa[6*stride+base+j];
            const float j2  = soa[7*stride+base+j], j3  = soa[8*stride+base+j];
            const int   jgt = sgt[base + j];
            const int   jef = eff[(size_t)img*S2 + j];
#pragma unroll
            for (int u = 0; u < 4; ++u) {
                if (!act[u]) continue;                // wave-uniform
                if (rk[u] < jef) {
                    float iw = fminf(jx2, bx2[u]) - fmaxf(jx1, bx1[u]);
                    float ih = fminf(jy2, by2[u]) - fmaxf(jy1, by1[u]);
                    if (iw > 0.f && ih > 0.f) {
                        float d0 = j0 - f0[u], d1 = j1 - f1[u];
                        float d2 = j2 - f2[u], d3 = j3 - f3[u];
                        float diff = 0.25f*(d0*d0 + d1*d1 + d2*d2 + d3*d3);
                        bool check = diff < 0.1f;
                        bool same  = (jgt == bgt[u]);
                        if (same && !check)      { ps[u] += diff * jsc;       pn[u] += 1.f; }
                        else if (!same && check) { qs[u] += expf(-diff)*jsc;  qn[u] += 1.f; }
                    }
                }
            }
        }
        float sPull = 0.f, cPull = 0.f, sPush = 0.f, cPush = 0.f;
#pragma unroll
        for (int u = 0; u < 4; ++u) {
            if (!act[u]) continue;                    // wave-uniform
            float a0 = ps[u], a1 = pn[u], a2 = qs[u], a3 = qn[u];
            for (int o = 32; o > 0; o >>= 1) {
                a0 += __shfl_down(a0, o); a1 += __shfl_down(a1, o);
                a2 += __shfl_down(a2, o); a3 += __shfl_down(a3, o);
            }
            if (lane == 0) {
                if (a1 > 0.f) { sPull += a0 / a1; cPull += 1.f; }
                if (a3 > 0.f) { sPush += a2 / a3; cPush += 1.f; }
            }
        }
        if (lane == 0) {
            pw[wave][0] = sPull; pw[wave][1] = cPull;
            pw[wave][2] = sPush; pw[wave][3] = cPush;
        }
        __syncthreads();
        if (t == 0) {
            float a = 0, b = 0, c = 0, d = 0;
            for (int w = 0; w < NWAVES; ++w) {
                a += pw[w][0]; b += pw[w][1]; c += pw[w][2]; d += pw[w][3];
            }
            if (a != 0.f) atomicAdd(&acc[img*4+0], a);
            if (b != 0.f) atomicAdd(&acc[img*4+1], b);
            if (c != 0.f) atomicAdd(&acc[img*4+2], c);
            if (d != 0.f) atomicAdd(&acc[img*4+3], d);
        }
    }

    // ---- completion ticket; last block finalizes ----
    __syncthreads();
    __threadfence();
    if (t == 0) ticket = atomicAdd(done, 1);
    __syncthreads();
    if (ticket == PB * imgs - 1 && t == 0) {
        __threadfence();
        float push = 0.f, pull = 0.f;
        for (int i = 0; i < imgs; ++i) {
            pull += acc[i*4+0] / (acc[i*4+1] + 1e-6f);
            push += acc[i*4+2] / (acc[i*4+3] + 1e-6f);
        }
        out[0] = push / (float)imgs;   // push_loss
        out[1] = pull / (float)imgs;   // pull_loss
    }
}

// =====================================================================
// FALLBACK PATH (R1 kernel) — only if ws too small / N > 2048 / imgs > 8.
// =====================================================================
__global__ __launch_bounds__(BLOCK) void tagloss_kernel(
    const float* __restrict__ pred, const int* __restrict__ gt_inds,
    const float* __restrict__ proposals, float* __restrict__ ws, int N)
{
    const int img = blockIdx.x, t = threadIdx.x;
    const int lane = t & 63, wav = t >> 6;
    const float* P = proposals + (size_t)img * N * 5;
    const float* E = pred      + (size_t)img * N * 4;
    const int*   G = gt_inds   + (size_t)img * N;
    float x1[KMAX], y1[KMAX], x2[KMAX], y2[KMAX], sc[KMAX];
    float e0[KMAX], e1[KMAX], e2[KMAX], e3[KMAX];
    int gt[KMAX]; unsigned amask = 0u; int local_alive = 0;
#pragma unroll
    for (int k = 0; k < KMAX; ++k) {
        int j = k * BLOCK + t;
        if (j < N) {
            x1[k]=P[j*5+0]; y1[k]=P[j*5+1]; x2[k]=P[j*5+2]; y2[k]=P[j*5+3]; sc[k]=P[j*5+4];
            e0[k]=E[j*4+0]; e1[k]=E[j*4+1]; e2[k]=E[j*4+2]; e3[k]=E[j*4+3]; gt[k]=G[j];
            if (gt[k] >= 0 && (y2[k]-y1[k]) > 0.0f) { amask |= 1u<<k; local_alive++; }
        } else { x1[k]=y1[k]=x2[k]=y2[k]=0.f; sc[k]=0.f; e0[k]=e1[k]=e2[k]=e3[k]=0.f; gt[k]=-1; }
    }
    __shared__ unsigned long long s_key[NWAVES];
    __shared__ float s_b[9];
    __shared__ float s_part[NWAVES][5];
    int alive_count;
    {
        float v = (float)local_alive;
#pragma unroll
        for (int o = 32; o > 0; o >>= 1) v += __shfl_down(v, o);
        if (lane == 0) s_part[wav][0] = v;
        __syncthreads();
        float tot = 0.f;
        for (int w = 0; w < NWAVES; ++w) tot += s_part[w][0];
        alive_count = (int)tot;
    }
    float tot_pull=0.f, tot_push=0.f, pull_cnt=0.f, push_cnt=0.f;
    while (alive_count >= 2) {
        unsigned long long key = 0ull;
#pragma unroll
        for (int k = 0; k < KMAX; ++k)
            if (amask & (1u<<k)) {
                unsigned long long kk = ((unsigned long long)__float_as_uint(sc[k])<<32)
                                      | (unsigned long long)(0xFFFFFFFFu - (unsigned)(k*BLOCK+t));
                if (kk > key) key = kk;
            }
#pragma unroll
        for (int o = 32; o > 0; o >>= 1) {
            unsigned long long ok = __shfl_down(key, o);
            if (ok > key) key = ok;
        }
        if (lane == 0) s_key[wav] = key;
        __syncthreads();
        unsigned long long bk = s_key[0];
        for (int w = 1; w < NWAVES; ++w) if (s_key[w] > bk) bk = s_key[w];
        const int i = (int)(0xFFFFFFFFu - (unsigned)(bk & 0xFFFFFFFFull));
        if ((i & (BLOCK-1)) == t) {
            int k = i / BLOCK;
            s_b[0]=x1[k]; s_b[1]=y1[k]; s_b[2]=x2[k]; s_b[3]=y2[k];
            s_b[4]=e0[k]; s_b[5]=e1[k]; s_b[6]=e2[k]; s_b[7]=e3[k];
            s_b[8]=__int_as_float(gt[k]);
        }
        __syncthreads();
        const float bx1=s_b[0], by1=s_b[1], bx2=s_b[2], by2=s_b[3];
        const float f0=s_b[4], f1=s_b[5], f2=s_b[6], f3=s_b[7];
        const int bgt = __float_as_int(s_b[8]);
        const float areai = (bx2-bx1)*(by2-by1);
        float psum=0.f,qsum=0.f,pn=0.f,qn=0.f,scnt=0.f;
#pragma unroll
        for (int k = 0; k < KMAX; ++k) {
            if (!(amask & (1u<<k))) continue;
            int j = k*BLOCK+t;
            if (j == i) { amask &= ~(1u<<k); continue; }
            float iw = fmaxf(fminf(x2[k],bx2)-fmaxf(x1[k],bx1),0.f);
            float ih = fmaxf(fminf(y2[k],by2)-fmaxf(y1[k],by1),0.f);
            float inter = iw*ih;
            float uni = (x2[k]-x1[k])*(y2[k]-y1[k]) + areai - inter;
            float iou = inter / fmaxf(uni, 1e-12f);
            if (iou > 0.f) {
                float d0=e0[k]-f0,d1=e1[k]-f1,d2=e2[k]-f2,d3=e3[k]-f3;
                float diff = 0.25f*(d0*d0+d1*d1+d2*d2+d3*d3);
                bool check = diff < 0.1f;
                bool same = (gt[k]==bgt);
                if (same && !check) { psum += diff*sc[k]; pn += 1.f; }
                if (!same && check) { qsum += __expf(-diff)*sc[k]; qn += 1.f; }
                if (check)          { amask &= ~(1u<<k); scnt += 1.f; }
            }
        }
        float r0=psum,r1=pn,r2=qsum,r3=qn,r4=scnt;
#pragma unroll
        for (int o = 32; o > 0; o >>= 1) {
            r0+=__shfl_down(r0,o); r1+=__shfl_down(r1,o); r2+=__shfl_down(r2,o);
            r3+=__shfl_down(r3,o); r4+=__shfl_down(r4,o);
        }
        if (lane == 0) { s_part[wav][0]=r0;s_part[wav][1]=r1;s_part[wav][2]=r2;s_part[wav][3]=r3;s_part[wav][4]=r4; }
        __syncthreads();
        float T0=0,T1=0,T2=0,T3=0,T4=0;
        for (int w = 0; w < NWAVES; ++w) {
            T0+=s_part[w][0];T1+=s_part[w][1];T2+=s_part[w][2];T3+=s_part[w][3];T4+=s_part[w][4];
        }
        if (T1 > 0.f) { tot_pull += T0/T1; pull_cnt += 1.f; }
        if (T3 > 0.f) { tot_push += T2/T3; push_cnt += 1.f; }
        alive_count -= 1 + (int)T4;
    }
    if (t == 0) {
        ws[img*2+0] = tot_push / (push_cnt + 1e-6f);
        ws[img*2+1] = tot_pull / (pull_cnt + 1e-6f);
    }
}

__global__ void finalize_fb_kernel(const float* __restrict__ ws,
                                   float* __restrict__ out, int imgs)
{
    if (threadIdx.x == 0 && blockIdx.x == 0) {
        float push = 0.f, pull = 0.f;
        for (int k = 0; k < imgs; ++k) { push += ws[2*k]; pull += ws[2*k+1]; }
        out[0] = push / (float)imgs;
        out[1] = pull / (float)imgs;
    }
}

// =====================================================================
extern "C" void kernel_launch(void* const* d_in, const int* in_sizes, int n_in,
                              void* d_out, int out_size, void* d_ws, size_t ws_size,
                              hipStream_t stream) {
    const float* pred      = (const float*)d_in[0];
    const int*   gt_inds   = (const int*)  d_in[1];
    const float* proposals = (const float*)d_in[2];
    const int imgs = in_sizes[3] / 80;     // gt_bboxes (IMGS,20,4)
    const int N    = in_sizes[1] / imgs;   // gt_inds (IMGS,N)

    size_t off = 0;
    auto alloc = [&](size_t b) { size_t o = off; off += (b + 255) & ~(size_t)255; return o; };
    const size_t soa_off  = alloc((size_t)9 * imgs * S2 * 4);
    const size_t sgt_off  = alloc((size_t)imgs * S2 * 4);
    const size_t sel_off  = alloc((size_t)imgs * NW * 8);
    const size_t eff_off  = alloc((size_t)imgs * S2 * 4);
    const size_t nst_off  = alloc((size_t)imgs * 4);
    const size_t rnk_off  = alloc((size_t)imgs * RB * S2 * 4);
    const size_t prs_off  = alloc((size_t)imgs * PCAP * 4);
    const size_t pcn_off  = alloc((size_t)imgs * 4);
    const size_t acc_off  = alloc((size_t)imgs * 16);
    const size_t don_off  = alloc(4);
    const size_t need = off;

    if (N <= S2 && imgs <= 8 && ws_size >= need) {
        char* w = (char*)d_ws;
        float*              soa  = (float*)(w + soa_off);
        int*                sgt  = (int*)(w + sgt_off);
        unsigned long long* sel  = (unsigned long long*)(w + sel_off);
        int*                eff  = (int*)(w + eff_off);
        int*                nst  = (int*)(w + nst_off);
        int*                rnk  = (int*)(w + rnk_off);
        unsigned*           prs  = (unsigned*)(w + prs_off);
        int*                pcn  = (int*)(w + pcn_off);
        float*              acc  = (float*)(w + acc_off);
        int*                don  = (int*)(w + don_off);

        rankcount_kernel<<<dim3(RB, RB, imgs), BLOCK, 0, stream>>>(
            proposals, rnk, pcn, acc, don, N, imgs);
        rankscatter_kernel<<<dim3(RB, imgs), BLOCK, 0, stream>>>(
            pred, gt_inds, proposals, rnk, soa, sgt, N, imgs);
        suppairs_kernel<<<dim3(NCH, NCH, imgs), BLOCK, 0, stream>>>(
            soa, prs, pcn, N, imgs);
        greedyeff_kernel<<<imgs, BLOCK, 0, stream>>>(prs, pcn, sgt, soa,
                                                     sel, eff, nst, imgs);
        pairsfinal_kernel<<<dim3(PB, imgs), BLOCK, 0, stream>>>(
            soa, sgt, eff, sel, nst, acc, don, (float*)d_out, imgs);
    } else {
        float* ws = (float*)d_ws;
        tagloss_kernel<<<imgs, BLOCK, 0, stream>>>(pred, gt_inds, proposals, ws, N);
        finalize_fb_kernel<<<1, 64, 0, stream>>>(ws, (float*)d_out, imgs);
    }
}

// Round 16
// 141.137 us; speedup vs baseline: 2.1756x; 1.0807x over previous
//
#include <hip/hip_runtime.h>
#include <stdint.h>

#define BLOCK 256
#define KMAX 8
#define NWAVES (BLOCK / 64)
#define S2 2048          // padded N (pow2); N=2000 fits (11-bit indices)
#define NW 32            // 64-bit words per selection mask
#define NCH 32           // 64-element chunks
#define SPB 16           // selector slots per pairs-block
#define PB (S2 / SPB)    // pairs ic-blocks per image (128)
#define JS 4             // j-slices in pairsacc
#define JCH (NCH / JS)   // chunks per slice (8)
#define RB (S2 / BLOCK)  // rank tiles per axis (8)
#define PCAP 65536       // max suppression pairs per image (measured ~300)
#define LDSP2 4096       // pairs staged in LDS if P <= this (16 KB)
#define BCAP 64          // cross-chunk bucket capacity (expected ~9/chunk)
#define EFF_INF 0x7FFFFFFF

// =====================================================================
// K1a: rank counting (tiles bi x bj x img). Also zeroes pair counters and
// the per-selector accumulator table (stream order -> visible later).
// =====================================================================
__global__ __launch_bounds__(BLOCK) void rankcount_kernel(
    const float* __restrict__ proposals,
    int* __restrict__ partial, int* __restrict__ pcnt,
    float* __restrict__ selacc, int N, int imgs)
{
    const int bi = blockIdx.x, bj = blockIdx.y, img = blockIdx.z;
    const int t = threadIdx.x;
    if (bi == 0 && bj == 0 && img == 0 && t < imgs) pcnt[t] = 0;
    if (bj == 0) {                      // zero selacc: imgs*S2*4 floats
        const int id = img * RB + bi;   // [0, imgs*RB)
#pragma unroll
        for (int k = 0; k < 4; ++k)
            selacc[(size_t)id * 1024 + k * 256 + t] = 0.f;
    }
    const float* P = proposals + (size_t)img * N * 5;
    __shared__ unsigned sj[BLOCK];
    const int jbase = bj * BLOCK;
    {
        int j = jbase + t;
        sj[t] = (j < N) ? __float_as_uint(P[j*5 + 4]) : 0u;
    }
    __syncthreads();
    const int i = bi * BLOCK + t;
    if (i >= N) return;
    const unsigned my = __float_as_uint(P[i*5 + 4]);
    int p = 0;
    const uint4* s4 = (const uint4*)sj;
#pragma unroll
    for (int q = 0; q < BLOCK/4; ++q) {
        uint4 v = s4[q];
        int jj = jbase + q*4;
        p += (int)((v.x > my) | ((v.x == my) & (jj + 0 < i)));
        p += (int)((v.y > my) | ((v.y == my) & (jj + 1 < i)));
        p += (int)((v.z > my) | ((v.z == my) & (jj + 2 < i)));
        p += (int)((v.w > my) | ((v.w == my) & (jj + 3 < i)));
    }
    partial[((size_t)(img*RB + bj))*S2 + i] = p;
}

// =====================================================================
// K1b: sum partials -> position; gather payload; scatter to sorted SoA.
// =====================================================================
__global__ __launch_bounds__(BLOCK) void rankscatter_kernel(
    const float* __restrict__ pred, const int* __restrict__ gt_inds,
    const float* __restrict__ proposals, const int* __restrict__ partial,
    float* __restrict__ soa, int* __restrict__ sgt, int N, int imgs)
{
    const int img = blockIdx.y, t = threadIdx.x;
    const int i = blockIdx.x * BLOCK + t;
    const size_t stride = (size_t)imgs * S2;
    const size_t base   = (size_t)img * S2;

    if (i >= N) {
        if (i < S2) {
#pragma unroll
            for (int a = 0; a < 9; ++a) soa[(size_t)a*stride + base + i] = 0.f;
            sgt[base + i] = -1;
        }
        return;
    }

    const float* P = proposals + (size_t)img * N * 5;
    const float* E = pred      + (size_t)img * N * 4;
    const int*   G = gt_inds   + (size_t)img * N;

    const float p0 = P[i*5+0], p1 = P[i*5+1], p2 = P[i*5+2],
                p3 = P[i*5+3], p4 = P[i*5+4];
    const float q0 = E[i*4+0], q1 = E[i*4+1], q2 = E[i*4+2], q3 = E[i*4+3];
    const int   gg = G[i];

    int p = 0;
#pragma unroll
    for (int b = 0; b < RB; ++b)
        p += partial[((size_t)(img*RB + b))*S2 + i];

    soa[0*stride + base + p] = p0;
    soa[1*stride + base + p] = p1;
    soa[2*stride + base + p] = p2;
    soa[3*stride + base + p] = p3;
    soa[4*stride + base + p] = p4;
    soa[5*stride + base + p] = q0;
    soa[6*stride + base + p] = q1;
    soa[7*stride + base + p] = q2;
    soa[8*stride + base + p] = q3;
    sgt[base + p] = gg;
}

// =====================================================================
// K2: SPARSE suppression pairs, packed (lo<<11|hi), lo<hi.
// =====================================================================
__global__ __launch_bounds__(BLOCK) void suppairs_kernel(
    const float* __restrict__ soa, unsigned* __restrict__ pairs,
    int* __restrict__ pcnt, int N, int imgs)
{
    const int ic = blockIdx.x, jc = blockIdx.y, img = blockIdx.z;
    if (ic < jc) return;                 // i>j never holds there
    const int t = threadIdx.x, wave = t >> 6, lane = t & 63;
    const size_t stride = (size_t)imgs * S2, base = (size_t)img * S2;
    __shared__ float si[8][64];
    for (int idx = t; idx < 512; idx += BLOCK) {
        int f = idx >> 6, e = idx & 63;
        int a = (f < 4) ? f : f + 1;     // arrays {0,1,2,3,5,6,7,8}
        si[f][e] = soa[(size_t)a*stride + base + ic*64 + e];
    }
    __syncthreads();
    const int j = jc*64 + lane;
    const float jx1 = soa[0*stride+base+j], jy1 = soa[1*stride+base+j];
    const float jx2 = soa[2*stride+base+j], jy2 = soa[3*stride+base+j];
    const float j0  = soa[5*stride+base+j], j1  = soa[6*stride+base+j];
    const float j2  = soa[7*stride+base+j], j3  = soa[8*stride+base+j];
    const bool jin = (j < N);
    unsigned* PL = pairs + (size_t)img * PCAP;
    for (int ii = 0; ii < 16; ++ii) {
        int il = wave*16 + ii;
        int i  = ic*64 + il;
        bool s = false;
        if (jin && i < N && i > j) {
            float iw = fminf(jx2, si[2][il]) - fmaxf(jx1, si[0][il]);
            float ih = fminf(jy2, si[3][il]) - fmaxf(jy1, si[1][il]);
            if (iw > 0.f && ih > 0.f) {
                float d0 = j0-si[4][il], d1 = j1-si[5][il];
                float d2 = j2-si[6][il], d3 = j3-si[7][il];
                float diff = 0.25f*(d0*d0 + d1*d1 + d2*d2 + d3*d3);
                s = diff < 0.1f;   // TAG_THR
            }
        }
        unsigned long long m = __ballot(s);
        if (m) {
            int leader = __ffsll((unsigned long long)m) - 1;
            int basei = 0;
            if (lane == leader) basei = atomicAdd(&pcnt[img], __popcll(m));
            basei = __shfl(basei, leader);
            if (s) {
                int idx = basei + __popcll(m & ((lane == 0) ? 0ull : (~0ull >> (64 - lane))));
                if (idx < PCAP) PL[idx] = ((unsigned)j << 11) | (unsigned)i;  // lo=j, hi=i
            }
        }
    }
}

// =====================================================================
// K3: fused greedy + eff/nsteps. One 256-thread block per image.
// (Verified logic: single pass over pair list -> slocAll bitmask +
// cross-chunk buckets; pure-LDS ballot resolve; eff via min selected lo,
// ranks via prefix popcount. eff[i] == rank for selected i.)
// =====================================================================
__global__ __launch_bounds__(BLOCK) void greedyeff_kernel(
    const unsigned* __restrict__ pairs, const int* __restrict__ pcnt,
    const int* __restrict__ sgt, const float* __restrict__ soa,
    unsigned long long* __restrict__ selw, int* __restrict__ eff,
    int* __restrict__ nsteps, int imgs)
{
    const int img = blockIdx.x, t = threadIdx.x;
    const int lane = t & 63, wave = t >> 6;
    const size_t stride = (size_t)imgs * S2, base = (size_t)img * S2;

    __shared__ __align__(16) char A[16384];          // slocAll | sistar+hist
    __shared__ unsigned spair[LDSP2];                // 16 KB
    __shared__ unsigned bucket[NCH * BCAP];          // 8 KB
    __shared__ int bcnt[NCH];
    __shared__ unsigned long long skilled[NW], ssel[NW], svalid[NW];
    __shared__ int pfx[NW + 1];
    __shared__ unsigned wsum[NWAVES];
    __shared__ int bm[NWAVES];
    __shared__ int sV;

    unsigned long long* slocAll = (unsigned long long*)A;

    int P = pcnt[img]; if (P > PCAP) P = PCAP;
    const unsigned* PL = pairs + (size_t)img * PCAP;
    const bool staged = (P <= LDSP2);

    for (int x = t; x < S2; x += BLOCK) slocAll[x] = 0ull;
    if (t < NCH) bcnt[t] = 0;
    if (t == 0) sV = 0;
    __syncthreads();
    if (staged) for (int p = t; p < P; p += BLOCK) spair[p] = PL[p];
    for (int g = wave; g < NCH; g += NWAVES) {
        int j = g*64 + lane;
        int gv = sgt[base + j];
        float a = soa[1*stride + base + j];
        float b = soa[3*stride + base + j];
        bool invalid = !(gv >= 0 && (b - a) > 0.f);
        unsigned long long bb = __ballot(invalid);
        if (lane == 0) {
            skilled[g] = bb;
            svalid[g] = ~bb;
            atomicAdd(&sV, 64 - __popcll(bb));
        }
    }
    __syncthreads();
    for (int p = t; p < P; p += BLOCK) {
        unsigned v = staged ? spair[p] : PL[p];
        int lo = v >> 11, hi = v & 2047;
        if ((lo >> 6) == (hi >> 6)) {
            atomicOr(&slocAll[hi], 1ull << (lo & 63));
        } else {
            int idx = atomicAdd(&bcnt[lo >> 6], 1);
            if (idx < BCAP) bucket[(lo >> 6)*BCAP + idx] = v;
        }
    }
    __syncthreads();

    if (wave == 0) {
        const unsigned long long lowmask = (lane == 0) ? 0ull : (~0ull >> (64 - lane));
        for (int c = 0; c < NCH; ++c) {
            unsigned long long U = ~skilled[c];
            const unsigned long long loc = slocAll[c*64 + lane];
            unsigned long long sel = 0ull;
            while (U) {
                bool inU = (U >> lane) & 1ull;
                unsigned long long Am = __ballot(inU && ((loc & U & lowmask) == 0ull));
                sel |= Am;
                bool kill = inU && !((Am >> lane) & 1ull) && ((loc & Am) != 0ull);
                unsigned long long K = __ballot(kill);
                U &= ~(Am | K);
            }
            if (lane == 0) ssel[c] = sel;
            if (sel != 0ull) {
                const int bc = bcnt[c];
                if (bc <= BCAP) {
                    for (int q = lane; q < bc; q += 64) {
                        unsigned v = bucket[c*BCAP + q];
                        int lo = v >> 11, hi = v & 2047;
                        if ((sel >> (lo & 63)) & 1ull)
                            atomicOr(&skilled[hi >> 6], 1ull << (hi & 63));
                    }
                } else {
                    for (int p = lane; p < P; p += 64) {
                        unsigned v = PL[p];
                        int lo = v >> 11, hi = v & 2047;
                        if ((lo >> 6) == c && (hi >> 6) != c &&
                            ((sel >> (lo & 63)) & 1ull))
                            atomicOr(&skilled[hi >> 6], 1ull << (hi & 63));
                    }
                }
            }
        }
    }
    __syncthreads();
    if (t < NW) selw[(size_t)img*NW + t] = ssel[t];

    // ---- eff/nsteps (reuse A as sistar + hist) ----
    int* sistar = (int*)A;                   // 8 KB
    unsigned* hist = (unsigned*)(A + 8192);  // 8 KB
    for (int x = t; x < S2; x += BLOCK) { sistar[x] = EFF_INF; hist[x] = 0u; }
    if (t == 0) {
        int s = 0;
        for (int w = 0; w < NW; ++w) { pfx[w] = s; s += __popcll(ssel[w]); }
        pfx[NW] = s;
    }
    __syncthreads();
    for (int p = t; p < P; p += BLOCK) {
        unsigned v = staged ? spair[p] : PL[p];
        int lo = v >> 11, hi = v & 2047;
        if ((ssel[lo >> 6] >> (lo & 63)) & 1ull) atomicMin(&sistar[hi], lo);
    }
    __syncthreads();
#pragma unroll
    for (int k = 0; k < 8; ++k) {
        const int j = k*BLOCK + t;
        const int jw = j >> 6, jb = j & 63;
        bool valid = (svalid[jw] >> jb) & 1ull;
        bool selb  = (ssel[jw] >> jb) & 1ull;
        int e;
        if (!valid) e = 0;
        else if (selb)
            e = pfx[jw] + __popcll(ssel[jw] & (jb ? (~0ull >> (64 - jb)) : 0ull));
        else {
            int is = sistar[j];
            if (is == EFF_INF) e = EFF_INF;
            else {
                int iw_ = is >> 6, ib = is & 63;
                e = pfx[iw_] + __popcll(ssel[iw_] & (ib ? (~0ull >> (64 - ib)) : 0ull)) + 1;
                atomicAdd(&hist[e - 1], 1u);
            }
        }
        eff[(size_t)img*S2 + j] = e;
    }
    __syncthreads();

    const int V = sV, Sc = pfx[NW];
    unsigned loc8[8]; unsigned s = 0;
#pragma unroll
    for (int k = 0; k < 8; ++k) { s += hist[t*8 + k]; loc8[k] = s; }
    unsigned tot = s;
    for (int o = 1; o < 64; o <<= 1) {
        unsigned u = __shfl_up(tot, o);
        if (lane >= o) tot += u;
    }
    if (lane == 63) wsum[wave] = tot;
    __syncthreads();
    unsigned woff = 0;
    for (int w = 0; w < wave; ++w) woff += wsum[w];
    unsigned exclP = woff + tot - s;
    __syncthreads();
#pragma unroll
    for (int k = 0; k < 8; ++k) hist[t*8 + k] = exclP + loc8[k];
    __syncthreads();
    int best = EFF_INF;
    for (int r = t; r < Sc; r += BLOCK) {
        unsigned rem = (r == 0) ? 0u : hist[r - 1];
        int alive = V - r - (int)rem;
        if (alive < 2) best = min(best, r);
    }
    for (int o = 32; o > 0; o >>= 1) best = min(best, __shfl_down(best, o));
    if (lane == 0) bm[wave] = best;
    __syncthreads();
    if (t == 0) {
        int b = bm[0];
        for (int w = 1; w < NWAVES; ++w) b = min(b, bm[w]);
        nsteps[img] = min(b, Sc);
    }
}

// =====================================================================
// K4: per-selector accumulation, j-split for parallelism. Grid
// (ic, j-slice, img) = 2048 blocks; each wave owns 4 selector slots in
// registers and streams 8 j-chunks. Partial (ps,pn,qs,qn) -> atomicAdd
// into selacc[img][i][4] (<=JS contenders per address). Rank of selected
// i comes free: eff[i] == rank.
// =====================================================================
__global__ __launch_bounds__(BLOCK) void pairsacc_kernel(
    const float* __restrict__ soa, const int* __restrict__ sgt,
    const int* __restrict__ eff, const unsigned long long* __restrict__ selw,
    const int* __restrict__ nsteps, float* __restrict__ selacc, int imgs)
{
    const int ic = blockIdx.x, js = blockIdx.y, img = blockIdx.z;
    const int t = threadIdx.x, wave = t >> 6, lane = t & 63;
    const size_t stride = (size_t)imgs * S2, base = (size_t)img * S2;
    __shared__ unsigned long long ss[NW];
    __shared__ int anyact;
    if (t < NW) ss[t] = selw[(size_t)img*NW + t];
    if (t == 0) anyact = 0;
    __syncthreads();
    const int ns = nsteps[img];

    float bx1[4], by1[4], bx2[4], by2[4], f0[4], f1[4], f2[4], f3[4];
    int bgt[4], rk[4]; bool act[4];
    bool any = false;
#pragma unroll
    for (int u = 0; u < 4; ++u) {
        const int i = ic*SPB + wave*4 + u;
        bool selb = (ss[i >> 6] >> (i & 63)) & 1ull;
        int e = eff[(size_t)img*S2 + i];     // == rank for selected i
        rk[u] = e;
        act[u] = selb && (e < ns);
        any |= act[u];
        if (act[u]) {
            bx1[u] = soa[0*stride+base+i]; by1[u] = soa[1*stride+base+i];
            bx2[u] = soa[2*stride+base+i]; by2[u] = soa[3*stride+base+i];
            f0[u]  = soa[5*stride+base+i]; f1[u]  = soa[6*stride+base+i];
            f2[u]  = soa[7*stride+base+i]; f3[u]  = soa[8*stride+base+i];
            bgt[u] = sgt[base + i];
        } else {
            bx1[u]=by1[u]=bx2[u]=by2[u]=0.f; f0[u]=f1[u]=f2[u]=f3[u]=0.f; bgt[u]=-2;
        }
    }
    if (any && lane == 0) anyact = 1;   // benign same-value race
    __syncthreads();
    if (!anyact) return;                // selacc pre-zeroed

    float ps[4] = {0,0,0,0}, pn[4] = {0,0,0,0};
    float qs[4] = {0,0,0,0}, qn[4] = {0,0,0,0};
    for (int jt = 0; jt < JCH; ++jt) {
        const int j = (js*JCH + jt)*64 + lane;
        const float jx1 = soa[0*stride+base+j], jy1 = soa[1*stride+base+j];
        const float jx2 = soa[2*stride+base+j], jy2 = soa[3*stride+base+j];
        const float jsc = soa[4*stride+base+j];
        const float j0  = soa[5*stride+base+j], j1  = soa[6*stride+base+j];
        const float j2  = soa[7*stride+base+j], j3  = soa[8*stride+base+j];
        const int   jgt = sgt[base + j];
        const int   jef = eff[(size_t)img*S2 + j];
#pragma unroll
        for (int u = 0; u < 4; ++u) {
            if (!act[u]) continue;                    // wave-uniform
            if (rk[u] < jef) {                        // j alive (self excluded: jef==rk)
                float iw = fminf(jx2, bx2[u]) - fmaxf(jx1, bx1[u]);
                float ih = fminf(jy2, by2[u]) - fmaxf(jy1, by1[u]);
                if (iw > 0.f && ih > 0.f) {
                    float d0 = j0 - f0[u], d1 = j1 - f1[u];
                    float d2 = j2 - f2[u], d3 = j3 - f3[u];
                    float diff = 0.25f*(d0*d0 + d1*d1 + d2*d2 + d3*d3);
                    bool check = diff < 0.1f;
                    bool same  = (jgt == bgt[u]);
                    if (same && !check)      { ps[u] += diff * jsc;       pn[u] += 1.f; }
                    else if (!same && check) { qs[u] += expf(-diff)*jsc;  qn[u] += 1.f; }
                }
            }
        }
    }
#pragma unroll
    for (int u = 0; u < 4; ++u) {
        if (!act[u]) continue;                        // wave-uniform
        float a0 = ps[u], a1 = pn[u], a2 = qs[u], a3 = qn[u];
        for (int o = 32; o > 0; o >>= 1) {
            a0 += __shfl_down(a0, o); a1 += __shfl_down(a1, o);
            a2 += __shfl_down(a2, o); a3 += __shfl_down(a3, o);
        }
        if (lane == 0) {
            const int i = ic*SPB + wave*4 + u;
            float* p = selacc + ((size_t)img*S2 + i) * 4;
            if (a1 != 0.f) atomicAdd(&p[0], a0);
            if (a1 != 0.f) atomicAdd(&p[1], a1);
            if (a3 != 0.f) atomicAdd(&p[2], a2);
            if (a3 != 0.f) atomicAdd(&p[3], a3);
        }
    }
}

// =====================================================================
// K5: form per-selector ratios and final losses. One block.
// =====================================================================
__global__ __launch_bounds__(BLOCK) void ratiofinal_kernel(
    const float* __restrict__ selacc, float* __restrict__ out, int imgs)
{
    const int t = threadIdx.x;
    __shared__ float a[8][4];
    if (t < 32) ((float*)a)[t] = 0.f;
    __syncthreads();
    for (int e = t; e < imgs * S2; e += BLOCK) {
        const float4 v = ((const float4*)selacc)[e];
        const int img = e >> 11;                     // S2 == 2048
        if (v.y > 0.f) { atomicAdd(&a[img][0], v.x / v.y); atomicAdd(&a[img][1], 1.f); }
        if (v.w > 0.f) { atomicAdd(&a[img][2], v.z / v.w); atomicAdd(&a[img][3], 1.f); }
    }
    __syncthreads();
    if (t == 0) {
        float push = 0.f, pull = 0.f;
        for (int i = 0; i < imgs; ++i) {
            pull += a[i][0] / (a[i][1] + 1e-6f);
            push += a[i][2] / (a[i][3] + 1e-6f);
        }
        out[0] = push / (float)imgs;   // push_loss
        out[1] = pull / (float)imgs;   // pull_loss
    }
}

// =====================================================================
// FALLBACK PATH (R1 kernel) — only if ws too small / N > 2048 / imgs > 8.
// =====================================================================
__global__ __launch_bounds__(BLOCK) void tagloss_kernel(
    const float* __restrict__ pred, const int* __restrict__ gt_inds,
    const float* __restrict__ proposals, float* __restrict__ ws, int N)
{
    const int img = blockIdx.x, t = threadIdx.x;
    const int lane = t & 63, wav = t >> 6;
    const float* P = proposals + (size_t)img * N * 5;
    const float* E = pred      + (size_t)img * N * 4;
    const int*   G = gt_inds   + (size_t)img * N;
    float x1[KMAX], y1[KMAX], x2[KMAX], y2[KMAX], sc[KMAX];
    float e0[KMAX], e1[KMAX], e2[KMAX], e3[KMAX];
    int gt[KMAX]; unsigned amask = 0u; int local_alive = 0;
#pragma unroll
    for (int k = 0; k < KMAX; ++k) {
        int j = k * BLOCK + t;
        if (j < N) {
            x1[k]=P[j*5+0]; y1[k]=P[j*5+1]; x2[k]=P[j*5+2]; y2[k]=P[j*5+3]; sc[k]=P[j*5+4];
            e0[k]=E[j*4+0]; e1[k]=E[j*4+1]; e2[k]=E[j*4+2]; e3[k]=E[j*4+3]; gt[k]=G[j];
            if (gt[k] >= 0 && (y2[k]-y1[k]) > 0.0f) { amask |= 1u<<k; local_alive++; }
        } else { x1[k]=y1[k]=x2[k]=y2[k]=0.f; sc[k]=0.f; e0[k]=e1[k]=e2[k]=e3[k]=0.f; gt[k]=-1; }
    }
    __shared__ unsigned long long s_key[NWAVES];
    __shared__ float s_b[9];
    __shared__ float s_part[NWAVES][5];
    int alive_count;
    {
        float v = (float)local_alive;
#pragma unroll
        for (int o = 32; o > 0; o >>= 1) v += __shfl_down(v, o);
        if (lane == 0) s_part[wav][0] = v;
        __syncthreads();
        float tot = 0.f;
        for (int w = 0; w < NWAVES; ++w) tot += s_part[w][0];
        alive_count = (int)tot;
    }
    float tot_pull=0.f, tot_push=0.f, pull_cnt=0.f, push_cnt=0.f;
    while (alive_count >= 2) {
        unsigned long long key = 0ull;
#pragma unroll
        for (int k = 0; k < KMAX; ++k)
            if (amask & (1u<<k)) {
                unsigned long long kk = ((unsigned long long)__float_as_uint(sc[k])<<32)
                                      | (unsigned long long)(0xFFFFFFFFu - (unsigned)(k*BLOCK+t));
                if (kk > key) key = kk;
            }
#pragma unroll
        for (int o = 32; o > 0; o >>= 1) {
            unsigned long long ok = __shfl_down(key, o);
            if (ok > key) key = ok;
        }
        if (lane == 0) s_key[wav] = key;
        __syncthreads();
        unsigned long long bk = s_key[0];
        for (int w = 1; w < NWAVES; ++w) if (s_key[w] > bk) bk = s_key[w];
        const int i = (int)(0xFFFFFFFFu - (unsigned)(bk & 0xFFFFFFFFull));
        if ((i & (BLOCK-1)) == t) {
            int k = i / BLOCK;
            s_b[0]=x1[k]; s_b[1]=y1[k]; s_b[2]=x2[k]; s_b[3]=y2[k];
            s_b[4]=e0[k]; s_b[5]=e1[k]; s_b[6]=e2[k]; s_b[7]=e3[k];
            s_b[8]=__int_as_float(gt[k]);
        }
        __syncthreads();
        const float bx1=s_b[0], by1=s_b[1], bx2=s_b[2], by2=s_b[3];
        const float f0=s_b[4], f1=s_b[5], f2=s_b[6], f3=s_b[7];
        const int bgt = __float_as_int(s_b[8]);
        const float areai = (bx2-bx1)*(by2-by1);
        float psum=0.f,qsum=0.f,pn=0.f,qn=0.f,scnt=0.f;
#pragma unroll
        for (int k = 0; k < KMAX; ++k) {
            if (!(amask & (1u<<k))) continue;
            int j = k*BLOCK+t;
            if (j == i) { amask &= ~(1u<<k); continue; }
            float iw = fmaxf(fminf(x2[k],bx2)-fmaxf(x1[k],bx1),0.f);
            float ih = fmaxf(fminf(y2[k],by2)-fmaxf(y1[k],by1),0.f);
            float inter = iw*ih;
            float uni = (x2[k]-x1[k])*(y2[k]-y1[k]) + areai - inter;
            float iou = inter / fmaxf(uni, 1e-12f);
            if (iou > 0.f) {
                float d0=e0[k]-f0,d1=e1[k]-f1,d2=e2[k]-f2,d3=e3[k]-f3;
                float diff = 0.25f*(d0*d0+d1*d1+d2*d2+d3*d3);
                bool check = diff < 0.1f;
                bool same = (gt[k]==bgt);
                if (same && !check) { psum += diff*sc[k]; pn += 1.f; }
                if (!same && check) { qsum += __expf(-diff)*sc[k]; qn += 1.f; }
                if (check)          { amask &= ~(1u<<k); scnt += 1.f; }
            }
        }
        float r0=psum,r1=pn,r2=qsum,r3=qn,r4=scnt;
#pragma unroll
        for (int o = 32; o > 0; o >>= 1) {
            r0+=__shfl_down(r0,o); r1+=__shfl_down(r1,o); r2+=__shfl_down(r2,o);
            r3+=__shfl_down(r3,o); r4+=__shfl_down(r4,o);
        }
        if (lane == 0) { s_part[wav][0]=r0;s_part[wav][1]=r1;s_part[wav][2]=r2;s_part[wav][3]=r3;s_part[wav][4]=r4; }
        __syncthreads();
        float T0=0,T1=0,T2=0,T3=0,T4=0;
        for (int w = 0; w < NWAVES; ++w) {
            T0+=s_part[w][0];T1+=s_part[w][1];T2+=s_part[w][2];T3+=s_part[w][3];T4+=s_part[w][4];
        }
        if (T1 > 0.f) { tot_pull += T0/T1; pull_cnt += 1.f; }
        if (T3 > 0.f) { tot_push += T2/T3; push_cnt += 1.f; }
        alive_count -= 1 + (int)T4;
    }
    if (t == 0) {
        ws[img*2+0] = tot_push / (push_cnt + 1e-6f);
        ws[img*2+1] = tot_pull / (pull_cnt + 1e-6f);
    }
}

__global__ void finalize_fb_kernel(const float* __restrict__ ws,
                                   float* __restrict__ out, int imgs)
{
    if (threadIdx.x == 0 && blockIdx.x == 0) {
        float push = 0.f, pull = 0.f;
        for (int k = 0; k < imgs; ++k) { push += ws[2*k]; pull += ws[2*k+1]; }
        out[0] = push / (float)imgs;
        out[1] = pull / (float)imgs;
    }
}

// =====================================================================
extern "C" void kernel_launch(void* const* d_in, const int* in_sizes, int n_in,
                              void* d_out, int out_size, void* d_ws, size_t ws_size,
                              hipStream_t stream) {
    const float* pred      = (const float*)d_in[0];
    const int*   gt_inds   = (const int*)  d_in[1];
    const float* proposals = (const float*)d_in[2];
    const int imgs = in_sizes[3] / 80;     // gt_bboxes (IMGS,20,4)
    const int N    = in_sizes[1] / imgs;   // gt_inds (IMGS,N)

    size_t off = 0;
    auto alloc = [&](size_t b) { size_t o = off; off += (b + 255) & ~(size_t)255; return o; };
    const size_t soa_off  = alloc((size_t)9 * imgs * S2 * 4);
    const size_t sgt_off  = alloc((size_t)imgs * S2 * 4);
    const size_t sel_off  = alloc((size_t)imgs * NW * 8);
    const size_t eff_off  = alloc((size_t)imgs * S2 * 4);
    const size_t nst_off  = alloc((size_t)imgs * 4);
    const size_t rnk_off  = alloc((size_t)imgs * RB * S2 * 4);
    const size_t prs_off  = alloc((size_t)imgs * PCAP * 4);
    const size_t pcn_off  = alloc((size_t)imgs * 4);
    const size_t sac_off  = alloc((size_t)imgs * S2 * 16);
    const size_t need = off;

    if (N <= S2 && imgs <= 8 && ws_size >= need) {
        char* w = (char*)d_ws;
        float*              soa  = (float*)(w + soa_off);
        int*                sgt  = (int*)(w + sgt_off);
        unsigned long long* sel  = (unsigned long long*)(w + sel_off);
        int*                eff  = (int*)(w + eff_off);
        int*                nst  = (int*)(w + nst_off);
        int*                rnk  = (int*)(w + rnk_off);
        unsigned*           prs  = (unsigned*)(w + prs_off);
        int*                pcn  = (int*)(w + pcn_off);
        float*              sac  = (float*)(w + sac_off);

        rankcount_kernel<<<dim3(RB, RB, imgs), BLOCK, 0, stream>>>(
            proposals, rnk, pcn, sac, N, imgs);
        rankscatter_kernel<<<dim3(RB, imgs), BLOCK, 0, stream>>>(
            pred, gt_inds, proposals, rnk, soa, sgt, N, imgs);
        suppairs_kernel<<<dim3(NCH, NCH, imgs), BLOCK, 0, stream>>>(
            soa, prs, pcn, N, imgs);
        greedyeff_kernel<<<imgs, BLOCK, 0, stream>>>(prs, pcn, sgt, soa,
                                                     sel, eff, nst, imgs);
        pairsacc_kernel<<<dim3(PB, JS, imgs), BLOCK, 0, stream>>>(
            soa, sgt, eff, sel, nst, sac, imgs);
        ratiofinal_kernel<<<1, BLOCK, 0, stream>>>(sac, (float*)d_out, imgs);
    } else {
        float* ws = (float*)d_ws;
        tagloss_kernel<<<imgs, BLOCK, 0, stream>>>(pred, gt_inds, proposals, ws, N);
        finalize_fb_kernel<<<1, 64, 0, stream>>>(ws, (float*)d_out, imgs);
    }
}